// Round 10
// baseline (360.481 us; speedup 1.0000x reference)
//
#include <hip/hip_runtime.h>

// GaussianActionField: out[b][k][y] = sum_n exp(-(x[b]·P[n,:,k] - posP[n][k])^2 / (2 s^2)) * color[n][y]
// B=256 N=65536 XD=32 YD=64 K=8.
// Dense attention-style (R8 structure, verified) + T14 register prefetch:
//   screen GEMM (swapped: S^T = P·x, exact via 2x2 bf16 split, 4 MFMA) -> in-register
//   exp2 -> cvt_pk to bf16 -> PV GEMM (out^T = color^T · G), K=16 zero-padded.
//   Global loads for chunk c+1 issued into registers during COMPUTE(c).
// gaf_pre: meta[n][k] = (posP, -log2e/(2 s^2)) table (4 MB in ws).
// gaf_reduce: out = sum over NR partials.

typedef __attribute__((ext_vector_type(8))) short short8;
typedef __attribute__((ext_vector_type(4))) float f32x4;

#define NTOT   65536
#define XD     32
#define YD     64
#define KK     8
#define META_BYTES (NTOT*KK*8)     // float2 per (n,k) = 4 MB
#define PART_FLOATS 32768          // per block: 64b x 8k x 64y
#define NCHUNKS 2048               // 32-n chunks

__device__ __forceinline__ unsigned short f2bf(float f) {   // fp32 -> bf16 RNE
  unsigned u = __float_as_uint(f);
  u += 0x7FFFu + ((u >> 16) & 1u);
  return (unsigned short)(u >> 16);
}

union FragU { unsigned u[4]; short8 s8; };

// ---------------- pre: posP + exponent scale table ----------------
__global__ __launch_bounds__(256)
void gaf_pre(const float* __restrict__ pos, const float* __restrict__ proj,
             const float* __restrict__ sig, float2* __restrict__ meta) {
  int gid = blockIdx.x * 256 + threadIdx.x;    // (n,k) flat
  int n = gid >> 3, k = gid & 7;
  const float*  pk = proj + (size_t)n * XD * KK + k;
  const float4* pg = (const float4*)(pos + (size_t)n * XD);
  float d = 0.f;
#pragma unroll
  for (int j = 0; j < 8; ++j) {
    float4 v = pg[j];
    d = fmaf(v.x, pk[(4*j+0)*KK], d);
    d = fmaf(v.y, pk[(4*j+1)*KK], d);
    d = fmaf(v.z, pk[(4*j+2)*KK], d);
    d = fmaf(v.w, pk[(4*j+3)*KK], d);
  }
  float s = sig[gid];
  meta[gid] = make_float2(d, -0.72134752044448169f / (s * s));
}

// ---------------- main: dense screen->exp->PV, register-fused ----------------
__global__ __launch_bounds__(512, 4)
void gaf_main(const float* __restrict__ x, const float* __restrict__ proj,
              const float* __restrict__ colr, const float2* __restrict__ meta,
              float* __restrict__ partial, int NCH) {
  // sPool: sPb0[256][40], sPb1[256][40] (u16), sCol[64][40] (u16); epilogue overlays it.
  __shared__ unsigned short sPool[2*256*40 + 64*40];   // 46080 B
  __shared__ float sPosP[8][36];
  __shared__ float sInv[8][36];
  unsigned short (*sPb0)[40] = (unsigned short(*)[40])sPool;
  unsigned short (*sPb1)[40] = (unsigned short(*)[40])(sPool + 256*40);
  unsigned short (*sCol)[40] = (unsigned short(*)[40])(sPool + 2*256*40);

  const int t = threadIdx.x, l = t & 63, w = t >> 6;
  const int sblk = blockIdx.x & 3, nr = blockIdx.x >> 2;
  const int bt = w & 3, k0 = (w >> 2) * 4;     // wave: b-tile bt, k's k0..k0+3
  const int lc = l & 15, lg = l >> 4;          // lane col / group
  const int cbeg = nr * NCH;
  int cend = cbeg + NCH; if (cend > NCHUNKS) cend = NCHUNKS;

  float* pb = partial + (size_t)blockIdx.x * PART_FLOATS;
  if (cbeg >= cend) {                          // idle block: zero partial
    float4 z = {0.f,0.f,0.f,0.f};
#pragma unroll
    for (int r = 0; r < PART_FLOATS/4/512; ++r) ((float4*)pb)[t + r*512] = z;
    return;
  }

  // x B-fragments (2-way bf16 split), wave's b-tile: lane holds x[b=lc][i=lg*8+j]
  short8 xf0, xf1;
  {
    const int brow = sblk*64 + bt*16 + lc;
    const float4* xr = (const float4*)(x + (size_t)brow*XD + lg*8);
    float4 u0 = xr[0], u1 = xr[1];
    float xv[8] = {u0.x,u0.y,u0.z,u0.w,u1.x,u1.y,u1.z,u1.w};
#pragma unroll
    for (int j = 0; j < 8; ++j) {
      unsigned u = __float_as_uint(xv[j]);
      unsigned short h0 = (unsigned short)(u >> 16);        // trunc
      float r1 = xv[j] - __uint_as_float(u & 0xFFFF0000u);  // exact
      xf0[j] = (short)h0;
      xf1[j] = (short)f2bf(r1);
    }
  }

  f32x4 acc[4][4];                             // [k-kk][y-subtile]
#pragma unroll
  for (int a = 0; a < 4; ++a)
#pragma unroll
    for (int b = 0; b < 4; ++b) acc[a][b] = (f32x4){0.f,0.f,0.f,0.f};

  const float4* colr4 = (const float4*)colr;

  // ---- T14 prefetch registers: chunk c+1's global loads issued during COMPUTE(c) ----
  float4 pv0, pv1, pv2, pv3, cpf; float2 mpf;
  auto PREF = [&](int c) {
    const float4* Pg = (const float4*)(proj + (size_t)c * 32 * XD * KK);
    pv0 = Pg[t];        pv1 = Pg[t + 512];
    pv2 = Pg[t + 1024]; pv3 = Pg[t + 1536];
    cpf = colr4[(size_t)c * 512 + t];
    if (t < 256) mpf = meta[(size_t)c * 256 + t];
  };

  PREF(cbeg);
  for (int c = cbeg; c < cend; ++c) {
    // ---- stage chunk c from prefetched registers (R8's staging code) ----
    { // colorT: [y][n] bf16
      int n = t >> 4, y4 = (t & 15) * 4;
      sCol[y4+0][n] = f2bf(cpf.x);
      sCol[y4+1][n] = f2bf(cpf.y);
      sCol[y4+2][n] = f2bf(cpf.z);
      sCol[y4+3][n] = f2bf(cpf.w);
    }
    if (t < 256) { sPosP[t&7][t>>3] = mpf.x; sInv[t&7][t>>3] = mpf.y; }
    { // P 2-way split -> sPb0/sPb1 [k*32+n][i]
      float4 pv[4] = {pv0, pv1, pv2, pv3};
#pragma unroll
      for (int r = 0; r < 4; ++r) {
        int f = t + r*512;
        int nn = f >> 6, i = (f & 63) >> 1, kk4 = (f & 1) * 4;
        float vj[4] = {pv[r].x, pv[r].y, pv[r].z, pv[r].w};
#pragma unroll
        for (int j = 0; j < 4; ++j) {
          unsigned u = __float_as_uint(vj[j]);
          int row = (kk4 + j)*32 + nn;
          sPb0[row][i] = (unsigned short)(u >> 16);
          sPb1[row][i] = f2bf(vj[j] - __uint_as_float(u & 0xFFFF0000u));
        }
      }
    }
    __syncthreads();                           // LDS ready
    if (c + 1 < cend) PREF(c + 1);             // overlap next chunk's loads with compute

    // ---- compute: screen (S^T) -> exp -> PV, all register-local (R8 verbatim) ----
#pragma unroll
    for (int kk = 0; kk < 4; ++kk) {
      const int k = k0 + kk;
#pragma unroll
      for (int s = 0; s < 2; ++s) {
        const int prow = k*32 + s*16 + lc;
        short8 p0 = *(const short8*)&sPb0[prow][lg*8];
        short8 p1 = *(const short8*)&sPb1[prow][lg*8];
        f32x4 S = (f32x4){0.f,0.f,0.f,0.f};
        S = __builtin_amdgcn_mfma_f32_16x16x32_bf16(p1, xf1, S, 0, 0, 0);
        S = __builtin_amdgcn_mfma_f32_16x16x32_bf16(p1, xf0, S, 0, 0, 0);
        S = __builtin_amdgcn_mfma_f32_16x16x32_bf16(p0, xf1, S, 0, 0, 0);
        S = __builtin_amdgcn_mfma_f32_16x16x32_bf16(p0, xf0, S, 0, 0, 0);
        // tail: g_r = exp2((S_r - posP)^2 * inv)   (underflow -> 0 handles cutoff)
        float4 pp = *(const float4*)&sPosP[k][s*16 + lg*4];
        float4 iv = *(const float4*)&sInv[k][s*16 + lg*4];
        float d0 = S[0]-pp.x, d1 = S[1]-pp.y, d2 = S[2]-pp.z, d3 = S[3]-pp.w;
        float g0 = __builtin_amdgcn_exp2f(d0*d0*iv.x);
        float g1 = __builtin_amdgcn_exp2f(d1*d1*iv.y);
        float g2 = __builtin_amdgcn_exp2f(d2*d2*iv.z);
        float g3 = __builtin_amdgcn_exp2f(d3*d3*iv.w);
        unsigned u0, u1;
        asm("v_cvt_pk_bf16_f32 %0, %1, %2" : "=v"(u0) : "v"(g0), "v"(g1));
        asm("v_cvt_pk_bf16_f32 %0, %1, %2" : "=v"(u1) : "v"(g2), "v"(g3));
        FragU gb; gb.u[0] = u0; gb.u[1] = u1; gb.u[2] = 0u; gb.u[3] = 0u;
        // PV: out^T[y][b] += color^T · G  (K=16 zero-padded into 16x16x32)
#pragma unroll
        for (int ys = 0; ys < 4; ++ys) {
          const uint2 a = *(const uint2*)&sCol[ys*16 + lc][s*16 + lg*4];
          FragU af; af.u[0] = a.x; af.u[1] = a.y; af.u[2] = 0u; af.u[3] = 0u;
          acc[kk][ys] = __builtin_amdgcn_mfma_f32_16x16x32_bf16(af.s8, gb.s8,
                                                                acc[kk][ys], 0, 0, 0);
        }
      }
    }
    __syncthreads();                           // compute done; next stage may overwrite
  }

  // ---- epilogue: transpose acc via LDS, coalesced partial write ----
  float* epi = (float*)sPool + w * (64*17);    // per-wave [64y][17] f32
#pragma unroll
  for (int kk = 0; kk < 4; ++kk) {
    const int k = k0 + kk;
#pragma unroll
    for (int ys = 0; ys < 4; ++ys) {
#pragma unroll
      for (int r = 0; r < 4; ++r)
        epi[(ys*16 + lg*4 + r)*17 + lc] = acc[kk][ys][r];
    }
    __syncthreads();
#pragma unroll
    for (int it = 0; it < 4; ++it) {
      int bi = it*4 + lg, y0 = lc*4;
      float4 v = { epi[(y0+0)*17 + bi], epi[(y0+1)*17 + bi],
                   epi[(y0+2)*17 + bi], epi[(y0+3)*17 + bi] };
      *(float4*)&pb[(size_t)(bt*16 + bi)*512 + k*64 + y0] = v;
    }
    __syncthreads();
  }
}

// ---------------- reduce: out = sum of NR partials ----------------
__global__ __launch_bounds__(512)
void gaf_reduce(const float* __restrict__ partial, float* __restrict__ out, int NR) {
  const int b = blockIdx.x;                    // global b
  const int s = b >> 6, bl = b & 63;
  const int t = threadIdx.x;                   // (k,y) flat 0..511
  float a0 = 0.f, a1 = 0.f, a2 = 0.f, a3 = 0.f;
  int nr = 0;
  for (; nr + 4 <= NR; nr += 4) {
    a0 += partial[(size_t)((nr+0)*4 + s)*PART_FLOATS + bl*512 + t];
    a1 += partial[(size_t)((nr+1)*4 + s)*PART_FLOATS + bl*512 + t];
    a2 += partial[(size_t)((nr+2)*4 + s)*PART_FLOATS + bl*512 + t];
    a3 += partial[(size_t)((nr+3)*4 + s)*PART_FLOATS + bl*512 + t];
  }
  for (; nr < NR; ++nr)
    a0 += partial[(size_t)(nr*4 + s)*PART_FLOATS + bl*512 + t];
  out[(size_t)b*512 + t] = (a0 + a1) + (a2 + a3);
}

extern "C" void kernel_launch(void* const* d_in, const int* in_sizes, int n_in,
                              void* d_out, int out_size, void* d_ws, size_t ws_size,
                              hipStream_t stream) {
  const float* x    = (const float*)d_in[0];
  const float* pos  = (const float*)d_in[1];
  const float* proj = (const float*)d_in[2];
  const float* colr = (const float*)d_in[3];
  const float* sig  = (const float*)d_in[4];
  float* out = (float*)d_out;

  float2* meta    = (float2*)d_ws;
  float*  partial = (float*)((char*)d_ws + META_BYTES);

  size_t avail = (ws_size > META_BYTES) ? ws_size - META_BYTES : 0;
  int NR = (int)(avail / (4ull * PART_FLOATS * 4ull));  // 512 KB per NR step
  if (NR > 128) NR = 128;
  if (NR < 1)  NR = 1;
  int NCH = (NCHUNKS + NR - 1) / NR;

  gaf_pre<<<(NTOT*KK)/256, 256, 0, stream>>>(pos, proj, sig, meta);
  gaf_main<<<4*NR, 512, 0, stream>>>(x, proj, colr, meta, partial, NCH);
  gaf_reduce<<<256, 512, 0, stream>>>(partial, out, NR);
}

// Round 11
// 199.508 us; speedup vs baseline: 1.8069x; 1.8069x over previous
//
#include <hip/hip_runtime.h>

// GaussianActionField: out[b][k][y] = sum_n exp(-(x[b]·P[n,:,k] - posP[n][k])^2 / (2 s^2)) * color[n][y]
// B=256 N=65536 XD=32 YD=64 K=8.
// Dense attention-style (R8 structure, verified) + global_load_lds P prefetch:
//   screen GEMM (swapped: S^T = P·x, exact via 2x2 bf16 split, 4 MFMA) -> in-register
//   exp2 -> cvt_pk to bf16 -> PV GEMM (out^T = color^T · G), K=16 zero-padded.
//   P for chunk c+1 DMA'd into raw LDS (zero VGPR) during COMPUTE(c); STAGE reads it
//   from LDS. Color+meta keep the small 6-reg prefetch (fits the 128-reg budget).
// gaf_pre: meta[n][k] = (posP, -log2e/(2 s^2)) table (4 MB in ws).
// gaf_reduce: out = sum over NR partials.

typedef __attribute__((ext_vector_type(8))) short short8;
typedef __attribute__((ext_vector_type(4))) float f32x4;

#define NTOT   65536
#define XD     32
#define YD     64
#define KK     8
#define META_BYTES (NTOT*KK*8)     // float2 per (n,k) = 4 MB
#define PART_FLOATS 32768          // per block: 64b x 8k x 64y
#define NCHUNKS 2048               // 32-n chunks

__device__ __forceinline__ unsigned short f2bf(float f) {   // fp32 -> bf16 RNE
  unsigned u = __float_as_uint(f);
  u += 0x7FFFu + ((u >> 16) & 1u);
  return (unsigned short)(u >> 16);
}

__device__ __forceinline__ void gload16(const void* g, void* l) {
  __builtin_amdgcn_global_load_lds(
      (const __attribute__((address_space(1))) unsigned*)g,
      (__attribute__((address_space(3))) unsigned*)l, 16, 0, 0);
}

union FragU { unsigned u[4]; short8 s8; };

// ---------------- pre: posP + exponent scale table ----------------
__global__ __launch_bounds__(256)
void gaf_pre(const float* __restrict__ pos, const float* __restrict__ proj,
             const float* __restrict__ sig, float2* __restrict__ meta) {
  int gid = blockIdx.x * 256 + threadIdx.x;    // (n,k) flat
  int n = gid >> 3, k = gid & 7;
  const float*  pk = proj + (size_t)n * XD * KK + k;
  const float4* pg = (const float4*)(pos + (size_t)n * XD);
  float d = 0.f;
#pragma unroll
  for (int j = 0; j < 8; ++j) {
    float4 v = pg[j];
    d = fmaf(v.x, pk[(4*j+0)*KK], d);
    d = fmaf(v.y, pk[(4*j+1)*KK], d);
    d = fmaf(v.z, pk[(4*j+2)*KK], d);
    d = fmaf(v.w, pk[(4*j+3)*KK], d);
  }
  float s = sig[gid];
  meta[gid] = make_float2(d, -0.72134752044448169f / (s * s));
}

// ---------------- main: dense screen->exp->PV, register-fused ----------------
__global__ __launch_bounds__(512, 4)
void gaf_main(const float* __restrict__ x, const float* __restrict__ proj,
              const float* __restrict__ colr, const float2* __restrict__ meta,
              float* __restrict__ partial, int NCH) {
  // sPool: sPb0[256][40], sPb1[256][40] (u16), sCol[64][40] (u16); epilogue overlays it.
  __shared__ unsigned short sPool[2*256*40 + 64*40];   // 46080 B
  __shared__ float sPosP[8][36];
  __shared__ float sInv[8][36];
  __shared__ __align__(16) float rawP[32*XD*KK];       // 32768 B raw P chunk (DMA dest)
  unsigned short (*sPb0)[40] = (unsigned short(*)[40])sPool;
  unsigned short (*sPb1)[40] = (unsigned short(*)[40])(sPool + 256*40);
  unsigned short (*sCol)[40] = (unsigned short(*)[40])(sPool + 2*256*40);

  const int t = threadIdx.x, l = t & 63, w = t >> 6;
  const int sblk = blockIdx.x & 3, nr = blockIdx.x >> 2;
  const int bt = w & 3, k0 = (w >> 2) * 4;     // wave: b-tile bt, k's k0..k0+3
  const int lc = l & 15, lg = l >> 4;          // lane col / group
  const int cbeg = nr * NCH;
  int cend = cbeg + NCH; if (cend > NCHUNKS) cend = NCHUNKS;

  float* pb = partial + (size_t)blockIdx.x * PART_FLOATS;
  if (cbeg >= cend) {                          // idle block: zero partial
    float4 z = {0.f,0.f,0.f,0.f};
#pragma unroll
    for (int r = 0; r < PART_FLOATS/4/512; ++r) ((float4*)pb)[t + r*512] = z;
    return;
  }

  // x B-fragments (2-way bf16 split), wave's b-tile: lane holds x[b=lc][i=lg*8+j]
  short8 xf0, xf1;
  {
    const int brow = sblk*64 + bt*16 + lc;
    const float4* xr = (const float4*)(x + (size_t)brow*XD + lg*8);
    float4 u0 = xr[0], u1 = xr[1];
    float xv[8] = {u0.x,u0.y,u0.z,u0.w,u1.x,u1.y,u1.z,u1.w};
#pragma unroll
    for (int j = 0; j < 8; ++j) {
      unsigned u = __float_as_uint(xv[j]);
      unsigned short h0 = (unsigned short)(u >> 16);        // trunc
      float r1 = xv[j] - __uint_as_float(u & 0xFFFF0000u);  // exact
      xf0[j] = (short)h0;
      xf1[j] = (short)f2bf(r1);
    }
  }

  f32x4 acc[4][4];                             // [k-kk][y-subtile]
#pragma unroll
  for (int a = 0; a < 4; ++a)
#pragma unroll
    for (int b = 0; b < 4; ++b) acc[a][b] = (f32x4){0.f,0.f,0.f,0.f};

  const float4* colr4 = (const float4*)colr;

  // P chunk DMA: wave-uniform LDS base + lane*16, linear copy (m97 pattern)
  auto ISSUE_P = [&](int c) {
    const float4* Pg = (const float4*)(proj + (size_t)c * 32 * XD * KK);
#pragma unroll
    for (int r = 0; r < 4; ++r)
      gload16(Pg + (t + r*512), &rawP[(w*64 + r*512) * 4]);
  };
  // small color+meta register prefetch (6 VGPRs, as R8)
  float4 cpf; float2 mpf;
  auto PREF_CM = [&](int c) {
    cpf = colr4[(size_t)c * 512 + t];
    if (t < 256) mpf = meta[(size_t)c * 256 + t];
  };

  ISSUE_P(cbeg);
  PREF_CM(cbeg);
  for (int c = cbeg; c < cend; ++c) {
    __syncthreads();                           // rawP[c] arrived; sPb free (compute done)
    // ---- stage chunk c: rawP (LDS) + cpf/mpf (regs) -> sPb/sCol/meta ----
    { // colorT: [y][n] bf16
      int n = t >> 4, y4 = (t & 15) * 4;
      sCol[y4+0][n] = f2bf(cpf.x);
      sCol[y4+1][n] = f2bf(cpf.y);
      sCol[y4+2][n] = f2bf(cpf.z);
      sCol[y4+3][n] = f2bf(cpf.w);
    }
    if (t < 256) { sPosP[t&7][t>>3] = mpf.x; sInv[t&7][t>>3] = mpf.y; }
    { // P 2-way split -> sPb0/sPb1 [k*32+n][i]   (R8 transform, source = rawP)
      const float4* raw4 = (const float4*)rawP;
#pragma unroll
      for (int r = 0; r < 4; ++r) {
        int f = t + r*512;
        float4 v = raw4[f];
        int nn = f >> 6, i = (f & 63) >> 1, kk4 = (f & 1) * 4;
        float vj[4] = {v.x, v.y, v.z, v.w};
#pragma unroll
        for (int j = 0; j < 4; ++j) {
          unsigned u = __float_as_uint(vj[j]);
          int row = (kk4 + j)*32 + nn;
          sPb0[row][i] = (unsigned short)(u >> 16);
          sPb1[row][i] = f2bf(vj[j] - __uint_as_float(u & 0xFFFF0000u));
        }
      }
    }
    __syncthreads();                           // sPb ready; rawP fully consumed
    if (c + 1 < cend) { ISSUE_P(c + 1); PREF_CM(c + 1); }   // overlap with compute

    // ---- compute: screen (S^T) -> exp -> PV, all register-local (R8 verbatim) ----
#pragma unroll
    for (int kk = 0; kk < 4; ++kk) {
      const int k = k0 + kk;
#pragma unroll
      for (int s = 0; s < 2; ++s) {
        const int prow = k*32 + s*16 + lc;
        short8 p0 = *(const short8*)&sPb0[prow][lg*8];
        short8 p1 = *(const short8*)&sPb1[prow][lg*8];
        f32x4 S = (f32x4){0.f,0.f,0.f,0.f};
        S = __builtin_amdgcn_mfma_f32_16x16x32_bf16(p1, xf1, S, 0, 0, 0);
        S = __builtin_amdgcn_mfma_f32_16x16x32_bf16(p1, xf0, S, 0, 0, 0);
        S = __builtin_amdgcn_mfma_f32_16x16x32_bf16(p0, xf1, S, 0, 0, 0);
        S = __builtin_amdgcn_mfma_f32_16x16x32_bf16(p0, xf0, S, 0, 0, 0);
        // tail: g_r = exp2((S_r - posP)^2 * inv)   (underflow -> 0 handles cutoff)
        float4 pp = *(const float4*)&sPosP[k][s*16 + lg*4];
        float4 iv = *(const float4*)&sInv[k][s*16 + lg*4];
        float d0 = S[0]-pp.x, d1 = S[1]-pp.y, d2 = S[2]-pp.z, d3 = S[3]-pp.w;
        float g0 = __builtin_amdgcn_exp2f(d0*d0*iv.x);
        float g1 = __builtin_amdgcn_exp2f(d1*d1*iv.y);
        float g2 = __builtin_amdgcn_exp2f(d2*d2*iv.z);
        float g3 = __builtin_amdgcn_exp2f(d3*d3*iv.w);
        unsigned u0, u1;
        asm("v_cvt_pk_bf16_f32 %0, %1, %2" : "=v"(u0) : "v"(g0), "v"(g1));
        asm("v_cvt_pk_bf16_f32 %0, %1, %2" : "=v"(u1) : "v"(g2), "v"(g3));
        FragU gb; gb.u[0] = u0; gb.u[1] = u1; gb.u[2] = 0u; gb.u[3] = 0u;
        // PV: out^T[y][b] += color^T · G  (K=16 zero-padded into 16x16x32)
#pragma unroll
        for (int ys = 0; ys < 4; ++ys) {
          const uint2 a = *(const uint2*)&sCol[ys*16 + lc][s*16 + lg*4];
          FragU af; af.u[0] = a.x; af.u[1] = a.y; af.u[2] = 0u; af.u[3] = 0u;
          acc[kk][ys] = __builtin_amdgcn_mfma_f32_16x16x32_bf16(af.s8, gb.s8,
                                                                acc[kk][ys], 0, 0, 0);
        }
      }
    }
  }
  __syncthreads();                             // compute done before epilogue overlay

  // ---- epilogue: transpose acc via LDS, coalesced partial write ----
  float* epi = (float*)sPool + w * (64*17);    // per-wave [64y][17] f32
#pragma unroll
  for (int kk = 0; kk < 4; ++kk) {
    const int k = k0 + kk;
#pragma unroll
    for (int ys = 0; ys < 4; ++ys) {
#pragma unroll
      for (int r = 0; r < 4; ++r)
        epi[(ys*16 + lg*4 + r)*17 + lc] = acc[kk][ys][r];
    }
    __syncthreads();
#pragma unroll
    for (int it = 0; it < 4; ++it) {
      int bi = it*4 + lg, y0 = lc*4;
      float4 v = { epi[(y0+0)*17 + bi], epi[(y0+1)*17 + bi],
                   epi[(y0+2)*17 + bi], epi[(y0+3)*17 + bi] };
      *(float4*)&pb[(size_t)(bt*16 + bi)*512 + k*64 + y0] = v;
    }
    __syncthreads();
  }
}

// ---------------- reduce: out = sum of NR partials ----------------
__global__ __launch_bounds__(512)
void gaf_reduce(const float* __restrict__ partial, float* __restrict__ out, int NR) {
  const int b = blockIdx.x;                    // global b
  const int s = b >> 6, bl = b & 63;
  const int t = threadIdx.x;                   // (k,y) flat 0..511
  float a0 = 0.f, a1 = 0.f, a2 = 0.f, a3 = 0.f;
  int nr = 0;
  for (; nr + 4 <= NR; nr += 4) {
    a0 += partial[(size_t)((nr+0)*4 + s)*PART_FLOATS + bl*512 + t];
    a1 += partial[(size_t)((nr+1)*4 + s)*PART_FLOATS + bl*512 + t];
    a2 += partial[(size_t)((nr+2)*4 + s)*PART_FLOATS + bl*512 + t];
    a3 += partial[(size_t)((nr+3)*4 + s)*PART_FLOATS + bl*512 + t];
  }
  for (; nr < NR; ++nr)
    a0 += partial[(size_t)(nr*4 + s)*PART_FLOATS + bl*512 + t];
  out[(size_t)b*512 + t] = (a0 + a1) + (a2 + a3);
}

extern "C" void kernel_launch(void* const* d_in, const int* in_sizes, int n_in,
                              void* d_out, int out_size, void* d_ws, size_t ws_size,
                              hipStream_t stream) {
  const float* x    = (const float*)d_in[0];
  const float* pos  = (const float*)d_in[1];
  const float* proj = (const float*)d_in[2];
  const float* colr = (const float*)d_in[3];
  const float* sig  = (const float*)d_in[4];
  float* out = (float*)d_out;

  float2* meta    = (float2*)d_ws;
  float*  partial = (float*)((char*)d_ws + META_BYTES);

  size_t avail = (ws_size > META_BYTES) ? ws_size - META_BYTES : 0;
  int NR = (int)(avail / (4ull * PART_FLOATS * 4ull));  // 512 KB per NR step
  if (NR > 128) NR = 128;
  if (NR < 1)  NR = 1;
  int NCH = (NCHUNKS + NR - 1) / NR;

  gaf_pre<<<(NTOT*KK)/256, 256, 0, stream>>>(pos, proj, sig, meta);
  gaf_main<<<4*NR, 512, 0, stream>>>(x, proj, colr, meta, partial, NCH);
  gaf_reduce<<<256, 512, 0, stream>>>(partial, out, NR);
}

// Round 12
// 164.478 us; speedup vs baseline: 2.1917x; 1.2130x over previous
//
#include <hip/hip_runtime.h>

// GaussianActionField: out[b][k][y] = sum_n exp(-(x[b]·P[n,:,k] - posP[n][k])^2 / (2 s^2)) * color[n][y]
// B=256 N=65536 XD=32 YD=64 K=8.
// Dense attention-style (R8 compute, verified) + global_load_lds P prefetch (R11) +
//   (R12a) NO register state held across compute: color/meta loaded inside STAGE,
//          issued before the P-split so their latency hides under LDS work.
//   (R12b) XCD sibling swizzle: the 4 b-set blocks sharing an n-range map to one XCD
//          so their P reads share that XCD's L2.
// gaf_pre: meta[n][k] = (posP, -log2e/(2 s^2)) table (4 MB in ws).
// gaf_reduce: out = sum over NR partials.

typedef __attribute__((ext_vector_type(8))) short short8;
typedef __attribute__((ext_vector_type(4))) float f32x4;

#define NTOT   65536
#define XD     32
#define YD     64
#define KK     8
#define META_BYTES (NTOT*KK*8)     // float2 per (n,k) = 4 MB
#define PART_FLOATS 32768          // per block: 64b x 8k x 64y
#define NCHUNKS 2048               // 32-n chunks

__device__ __forceinline__ unsigned short f2bf(float f) {   // fp32 -> bf16 RNE
  unsigned u = __float_as_uint(f);
  u += 0x7FFFu + ((u >> 16) & 1u);
  return (unsigned short)(u >> 16);
}

__device__ __forceinline__ void gload16(const void* g, void* l) {
  __builtin_amdgcn_global_load_lds(
      (const __attribute__((address_space(1))) unsigned*)g,
      (__attribute__((address_space(3))) unsigned*)l, 16, 0, 0);
}

union FragU { unsigned u[4]; short8 s8; };

// ---------------- pre: posP + exponent scale table ----------------
__global__ __launch_bounds__(256)
void gaf_pre(const float* __restrict__ pos, const float* __restrict__ proj,
             const float* __restrict__ sig, float2* __restrict__ meta) {
  int gid = blockIdx.x * 256 + threadIdx.x;    // (n,k) flat
  int n = gid >> 3, k = gid & 7;
  const float*  pk = proj + (size_t)n * XD * KK + k;
  const float4* pg = (const float4*)(pos + (size_t)n * XD);
  float d = 0.f;
#pragma unroll
  for (int j = 0; j < 8; ++j) {
    float4 v = pg[j];
    d = fmaf(v.x, pk[(4*j+0)*KK], d);
    d = fmaf(v.y, pk[(4*j+1)*KK], d);
    d = fmaf(v.z, pk[(4*j+2)*KK], d);
    d = fmaf(v.w, pk[(4*j+3)*KK], d);
  }
  float s = sig[gid];
  meta[gid] = make_float2(d, -0.72134752044448169f / (s * s));
}

// ---------------- main: dense screen->exp->PV, register-fused ----------------
__global__ __launch_bounds__(512, 4)
void gaf_main(const float* __restrict__ x, const float* __restrict__ proj,
              const float* __restrict__ colr, const float2* __restrict__ meta,
              float* __restrict__ partial, int NCH, int NR) {
  // sPool: sPb0[256][40], sPb1[256][40] (u16), sCol[64][40] (u16); epilogue overlays it.
  __shared__ unsigned short sPool[2*256*40 + 64*40];   // 46080 B
  __shared__ float sPosP[8][36];
  __shared__ float sInv[8][36];
  __shared__ __align__(16) float rawP[32*XD*KK];       // 32768 B raw P chunk (DMA dest)
  unsigned short (*sPb0)[40] = (unsigned short(*)[40])sPool;
  unsigned short (*sPb1)[40] = (unsigned short(*)[40])(sPool + 256*40);
  unsigned short (*sCol)[40] = (unsigned short(*)[40])(sPool + 2*256*40);

  const int t = threadIdx.x, l = t & 63, w = t >> 6;

  // ---- R12b: XCD sibling swizzle (bijective when NR%8==0) ----
  int nr, sblk;
  {
    const int gid = blockIdx.x;
    if ((NR & 7) == 0) {
      const int xcd = gid & 7, j = gid >> 3;   // consecutive gid round-robin XCDs
      nr   = xcd * (NR >> 3) + (j >> 2);       // 4 siblings share xcd
      sblk = j & 3;
    } else { nr = gid >> 2; sblk = gid & 3; }
  }

  const int bt = w & 3, k0 = (w >> 2) * 4;     // wave: b-tile bt, k's k0..k0+3
  const int lc = l & 15, lg = l >> 4;          // lane col / group
  const int cbeg = nr * NCH;
  int cend = cbeg + NCH; if (cend > NCHUNKS) cend = NCHUNKS;

  float* pb = partial + (size_t)(nr * 4 + sblk) * PART_FLOATS;   // logical slot
  if (cbeg >= cend) {                          // idle block: zero partial
    float4 z = {0.f,0.f,0.f,0.f};
#pragma unroll
    for (int r = 0; r < PART_FLOATS/4/512; ++r) ((float4*)pb)[t + r*512] = z;
    return;
  }

  // x B-fragments (2-way bf16 split), wave's b-tile: lane holds x[b=lc][i=lg*8+j]
  short8 xf0, xf1;
  {
    const int brow = sblk*64 + bt*16 + lc;
    const float4* xr = (const float4*)(x + (size_t)brow*XD + lg*8);
    float4 u0 = xr[0], u1 = xr[1];
    float xv[8] = {u0.x,u0.y,u0.z,u0.w,u1.x,u1.y,u1.z,u1.w};
#pragma unroll
    for (int j = 0; j < 8; ++j) {
      unsigned u = __float_as_uint(xv[j]);
      unsigned short h0 = (unsigned short)(u >> 16);        // trunc
      float r1 = xv[j] - __uint_as_float(u & 0xFFFF0000u);  // exact
      xf0[j] = (short)h0;
      xf1[j] = (short)f2bf(r1);
    }
  }

  f32x4 acc[4][4];                             // [k-kk][y-subtile]
#pragma unroll
  for (int a = 0; a < 4; ++a)
#pragma unroll
    for (int b = 0; b < 4; ++b) acc[a][b] = (f32x4){0.f,0.f,0.f,0.f};

  const float4* colr4 = (const float4*)colr;

  // P chunk DMA: wave-uniform LDS base + lane*16, linear copy (m97 pattern)
  auto ISSUE_P = [&](int c) {
    const float4* Pg = (const float4*)(proj + (size_t)c * 32 * XD * KK);
#pragma unroll
    for (int r = 0; r < 4; ++r)
      gload16(Pg + (t + r*512), &rawP[(w*64 + r*512) * 4]);
  };

  ISSUE_P(cbeg);
  for (int c = cbeg; c < cend; ++c) {
    __syncthreads();                           // rawP[c] arrived; sPb free (compute done)
    // ---- stage chunk c ----
    // issue small color/meta loads first; latency hides under the P-split below
    float4 cpf = colr4[(size_t)c * 512 + t];
    float2 mpf;
    if (t < 256) mpf = meta[(size_t)c * 256 + t];
    { // P 2-way split -> sPb0/sPb1 [k*32+n][i]   (source = rawP in LDS)
      const float4* raw4 = (const float4*)rawP;
#pragma unroll
      for (int r = 0; r < 4; ++r) {
        int f = t + r*512;
        float4 v = raw4[f];
        int nn = f >> 6, i = (f & 63) >> 1, kk4 = (f & 1) * 4;
        float vj[4] = {v.x, v.y, v.z, v.w};
#pragma unroll
        for (int j = 0; j < 4; ++j) {
          unsigned u = __float_as_uint(vj[j]);
          int row = (kk4 + j)*32 + nn;
          sPb0[row][i] = (unsigned short)(u >> 16);
          sPb1[row][i] = f2bf(vj[j] - __uint_as_float(u & 0xFFFF0000u));
        }
      }
    }
    { // colorT: [y][n] bf16
      int n = t >> 4, y4 = (t & 15) * 4;
      sCol[y4+0][n] = f2bf(cpf.x);
      sCol[y4+1][n] = f2bf(cpf.y);
      sCol[y4+2][n] = f2bf(cpf.z);
      sCol[y4+3][n] = f2bf(cpf.w);
    }
    if (t < 256) { sPosP[t&7][t>>3] = mpf.x; sInv[t&7][t>>3] = mpf.y; }
    __syncthreads();                           // sPb ready; rawP fully consumed
    if (c + 1 < cend) ISSUE_P(c + 1);          // DMA next chunk under compute (0 VGPR)

    // ---- compute: screen (S^T) -> exp -> PV, all register-local (R8 verbatim) ----
#pragma unroll
    for (int kk = 0; kk < 4; ++kk) {
      const int k = k0 + kk;
#pragma unroll
      for (int s = 0; s < 2; ++s) {
        const int prow = k*32 + s*16 + lc;
        short8 p0 = *(const short8*)&sPb0[prow][lg*8];
        short8 p1 = *(const short8*)&sPb1[prow][lg*8];
        f32x4 S = (f32x4){0.f,0.f,0.f,0.f};
        S = __builtin_amdgcn_mfma_f32_16x16x32_bf16(p1, xf1, S, 0, 0, 0);
        S = __builtin_amdgcn_mfma_f32_16x16x32_bf16(p1, xf0, S, 0, 0, 0);
        S = __builtin_amdgcn_mfma_f32_16x16x32_bf16(p0, xf1, S, 0, 0, 0);
        S = __builtin_amdgcn_mfma_f32_16x16x32_bf16(p0, xf0, S, 0, 0, 0);
        // tail: g_r = exp2((S_r - posP)^2 * inv)   (underflow -> 0 handles cutoff)
        float4 pp = *(const float4*)&sPosP[k][s*16 + lg*4];
        float4 iv = *(const float4*)&sInv[k][s*16 + lg*4];
        float d0 = S[0]-pp.x, d1 = S[1]-pp.y, d2 = S[2]-pp.z, d3 = S[3]-pp.w;
        float g0 = __builtin_amdgcn_exp2f(d0*d0*iv.x);
        float g1 = __builtin_amdgcn_exp2f(d1*d1*iv.y);
        float g2 = __builtin_amdgcn_exp2f(d2*d2*iv.z);
        float g3 = __builtin_amdgcn_exp2f(d3*d3*iv.w);
        unsigned u0, u1;
        asm("v_cvt_pk_bf16_f32 %0, %1, %2" : "=v"(u0) : "v"(g0), "v"(g1));
        asm("v_cvt_pk_bf16_f32 %0, %1, %2" : "=v"(u1) : "v"(g2), "v"(g3));
        FragU gb; gb.u[0] = u0; gb.u[1] = u1; gb.u[2] = 0u; gb.u[3] = 0u;
        // PV: out^T[y][b] += color^T · G  (K=16 zero-padded into 16x16x32)
#pragma unroll
        for (int ys = 0; ys < 4; ++ys) {
          const uint2 a = *(const uint2*)&sCol[ys*16 + lc][s*16 + lg*4];
          FragU af; af.u[0] = a.x; af.u[1] = a.y; af.u[2] = 0u; af.u[3] = 0u;
          acc[kk][ys] = __builtin_amdgcn_mfma_f32_16x16x32_bf16(af.s8, gb.s8,
                                                                acc[kk][ys], 0, 0, 0);
        }
      }
    }
  }
  __syncthreads();                             // compute done before epilogue overlay

  // ---- epilogue: transpose acc via LDS, coalesced partial write ----
  float* epi = (float*)sPool + w * (64*17);    // per-wave [64y][17] f32
#pragma unroll
  for (int kk = 0; kk < 4; ++kk) {
    const int k = k0 + kk;
#pragma unroll
    for (int ys = 0; ys < 4; ++ys) {
#pragma unroll
      for (int r = 0; r < 4; ++r)
        epi[(ys*16 + lg*4 + r)*17 + lc] = acc[kk][ys][r];
    }
    __syncthreads();
#pragma unroll
    for (int it = 0; it < 4; ++it) {
      int bi = it*4 + lg, y0 = lc*4;
      float4 v = { epi[(y0+0)*17 + bi], epi[(y0+1)*17 + bi],
                   epi[(y0+2)*17 + bi], epi[(y0+3)*17 + bi] };
      *(float4*)&pb[(size_t)(bt*16 + bi)*512 + k*64 + y0] = v;
    }
    __syncthreads();
  }
}

// ---------------- reduce: out = sum of NR partials ----------------
__global__ __launch_bounds__(512)
void gaf_reduce(const float* __restrict__ partial, float* __restrict__ out, int NR) {
  const int b = blockIdx.x;                    // global b
  const int s = b >> 6, bl = b & 63;
  const int t = threadIdx.x;                   // (k,y) flat 0..511
  float a0 = 0.f, a1 = 0.f, a2 = 0.f, a3 = 0.f;
  int nr = 0;
  for (; nr + 4 <= NR; nr += 4) {
    a0 += partial[(size_t)((nr+0)*4 + s)*PART_FLOATS + bl*512 + t];
    a1 += partial[(size_t)((nr+1)*4 + s)*PART_FLOATS + bl*512 + t];
    a2 += partial[(size_t)((nr+2)*4 + s)*PART_FLOATS + bl*512 + t];
    a3 += partial[(size_t)((nr+3)*4 + s)*PART_FLOATS + bl*512 + t];
  }
  for (; nr < NR; ++nr)
    a0 += partial[(size_t)(nr*4 + s)*PART_FLOATS + bl*512 + t];
  out[(size_t)b*512 + t] = (a0 + a1) + (a2 + a3);
}

extern "C" void kernel_launch(void* const* d_in, const int* in_sizes, int n_in,
                              void* d_out, int out_size, void* d_ws, size_t ws_size,
                              hipStream_t stream) {
  const float* x    = (const float*)d_in[0];
  const float* pos  = (const float*)d_in[1];
  const float* proj = (const float*)d_in[2];
  const float* colr = (const float*)d_in[3];
  const float* sig  = (const float*)d_in[4];
  float* out = (float*)d_out;

  float2* meta    = (float2*)d_ws;
  float*  partial = (float*)((char*)d_ws + META_BYTES);

  size_t avail = (ws_size > META_BYTES) ? ws_size - META_BYTES : 0;
  int NR = (int)(avail / (4ull * PART_FLOATS * 4ull));  // 512 KB per NR step
  if (NR > 128) NR = 128;
  if (NR < 1)  NR = 1;
  if (NR >= 8) NR &= ~7;                       // multiple of 8 for the XCD swizzle
  int NCH = (NCHUNKS + NR - 1) / NR;

  gaf_pre<<<(NTOT*KK)/256, 256, 0, stream>>>(pos, proj, sig, meta);
  gaf_main<<<4*NR, 512, 0, stream>>>(x, proj, colr, meta, partial, NCH, NR);
  gaf_reduce<<<256, 512, 0, stream>>>(partial, out, NR);
}

// Round 13
// 105.806 us; speedup vs baseline: 3.4070x; 1.5545x over previous
//
#include <hip/hip_runtime.h>

// GaussianActionField: out[b][k][y] = sum_n exp(-(x[b]·P[n,:,k] - posP[n][k])^2 / (2 s^2)) * color[n][y]
// B=256 N=65536 XD=32 YD=64 K=8.
// Dense attention-style (R12 verified structure):
//   screen GEMM (swapped: S^T = P·x, exact via 2x2 bf16 split, 4 MFMA) -> in-register
//   exp2 -> cvt_pk bf16 -> PV GEMM (out^T += color^T · G) at FULL K=32 (both 16-n
//   halves packed into one B-fragment; A uses the same K-permutation) [R13].
//   P DMA'd via global_load_lds into rawP (0 VGPR) during compute; STAGE splits it
//   with paired cvt_pk (1 op converts 2 elems AND forms the packed write word) [R13].
//   XCD sibling swizzle: 4 b-set blocks sharing an n-range land on one XCD's L2.
// gaf_pre: meta[n][k] = (posP, -log2e/(2 s^2)) table (4 MB in ws).
// gaf_reduce: out = sum over NR partials.

typedef __attribute__((ext_vector_type(8))) short short8;
typedef __attribute__((ext_vector_type(4))) float f32x4;

#define NTOT   65536
#define XD     32
#define YD     64
#define KK     8
#define META_BYTES (NTOT*KK*8)     // float2 per (n,k) = 4 MB
#define PART_FLOATS 32768          // per block: 64b x 8k x 64y
#define NCHUNKS 2048               // 32-n chunks

__device__ __forceinline__ unsigned short f2bf(float f) {   // fp32 -> bf16 RNE
  unsigned u = __float_as_uint(f);
  u += 0x7FFFu + ((u >> 16) & 1u);
  return (unsigned short)(u >> 16);
}

__device__ __forceinline__ void gload16(const void* g, void* l) {
  __builtin_amdgcn_global_load_lds(
      (const __attribute__((address_space(1))) unsigned*)g,
      (__attribute__((address_space(3))) unsigned*)l, 16, 0, 0);
}

union FragU { unsigned u[4]; short8 s8; };

// ---------------- pre: posP + exponent scale table ----------------
__global__ __launch_bounds__(256)
void gaf_pre(const float* __restrict__ pos, const float* __restrict__ proj,
             const float* __restrict__ sig, float2* __restrict__ meta) {
  int gid = blockIdx.x * 256 + threadIdx.x;    // (n,k) flat
  int n = gid >> 3, k = gid & 7;
  const float*  pk = proj + (size_t)n * XD * KK + k;
  const float4* pg = (const float4*)(pos + (size_t)n * XD);
  float d = 0.f;
#pragma unroll
  for (int j = 0; j < 8; ++j) {
    float4 v = pg[j];
    d = fmaf(v.x, pk[(4*j+0)*KK], d);
    d = fmaf(v.y, pk[(4*j+1)*KK], d);
    d = fmaf(v.z, pk[(4*j+2)*KK], d);
    d = fmaf(v.w, pk[(4*j+3)*KK], d);
  }
  float s = sig[gid];
  meta[gid] = make_float2(d, -0.72134752044448169f / (s * s));
}

// ---------------- main: dense screen->exp->PV, register-fused ----------------
__global__ __launch_bounds__(512, 4)
void gaf_main(const float* __restrict__ x, const float* __restrict__ proj,
              const float* __restrict__ colr, const float2* __restrict__ meta,
              float* __restrict__ partial, int NCH, int NR) {
  // sPool: sPb0[256][40], sPb1[256][40] (u16), sCol[64][40] (u16); epilogue overlays it.
  __shared__ unsigned short sPool[2*256*40 + 64*40];   // 46080 B
  __shared__ float sPosP[8][36];
  __shared__ float sInv[8][36];
  __shared__ __align__(16) float rawP[32*XD*KK];       // 32768 B raw P chunk (DMA dest)
  unsigned short (*sPb0)[40] = (unsigned short(*)[40])sPool;
  unsigned short (*sPb1)[40] = (unsigned short(*)[40])(sPool + 256*40);
  unsigned short (*sCol)[40] = (unsigned short(*)[40])(sPool + 2*256*40);

  const int t = threadIdx.x, l = t & 63, w = t >> 6;

  // ---- XCD sibling swizzle (bijective when NR%8==0) ----
  int nr, sblk;
  {
    const int gid = blockIdx.x;
    if ((NR & 7) == 0) {
      const int xcd = gid & 7, j = gid >> 3;   // consecutive gid round-robin XCDs
      nr   = xcd * (NR >> 3) + (j >> 2);       // 4 siblings share xcd
      sblk = j & 3;
    } else { nr = gid >> 2; sblk = gid & 3; }
  }

  const int bt = w & 3, k0 = (w >> 2) * 4;     // wave: b-tile bt, k's k0..k0+3
  const int lc = l & 15, lg = l >> 4;          // lane col / group
  const int cbeg = nr * NCH;
  int cend = cbeg + NCH; if (cend > NCHUNKS) cend = NCHUNKS;

  float* pb = partial + (size_t)(nr * 4 + sblk) * PART_FLOATS;   // logical slot
  if (cbeg >= cend) {                          // idle block: zero partial
    float4 z = {0.f,0.f,0.f,0.f};
#pragma unroll
    for (int r = 0; r < PART_FLOATS/4/512; ++r) ((float4*)pb)[t + r*512] = z;
    return;
  }

  // x B-fragments (2-way bf16 split), wave's b-tile: lane holds x[b=lc][i=lg*8+j]
  short8 xf0, xf1;
  {
    const int brow = sblk*64 + bt*16 + lc;
    const float4* xr = (const float4*)(x + (size_t)brow*XD + lg*8);
    float4 u0 = xr[0], u1 = xr[1];
    float xv[8] = {u0.x,u0.y,u0.z,u0.w,u1.x,u1.y,u1.z,u1.w};
#pragma unroll
    for (int j = 0; j < 8; ++j) {
      unsigned u = __float_as_uint(xv[j]);
      unsigned short h0 = (unsigned short)(u >> 16);        // trunc
      float r1 = xv[j] - __uint_as_float(u & 0xFFFF0000u);  // exact
      xf0[j] = (short)h0;
      xf1[j] = (short)f2bf(r1);
    }
  }

  f32x4 acc[4][4];                             // [k-kk][y-subtile]
#pragma unroll
  for (int a = 0; a < 4; ++a)
#pragma unroll
    for (int b = 0; b < 4; ++b) acc[a][b] = (f32x4){0.f,0.f,0.f,0.f};

  const float4* colr4 = (const float4*)colr;

  // P chunk DMA: wave-uniform LDS base + lane*16, linear copy (m97 pattern)
  auto ISSUE_P = [&](int c) {
    const float4* Pg = (const float4*)(proj + (size_t)c * 32 * XD * KK);
#pragma unroll
    for (int r = 0; r < 4; ++r)
      gload16(Pg + (t + r*512), &rawP[(w*64 + r*512) * 4]);
  };

  ISSUE_P(cbeg);
  for (int c = cbeg; c < cend; ++c) {
    __syncthreads();                           // rawP[c] arrived; sPb free (compute done)
    // ---- stage chunk c ----
    // issue small color/meta loads first; latency hides under the P-split below
    float4 cpf = colr4[(size_t)c * 512 + t];
    float2 mpf;
    if (t < 256) mpf = meta[(size_t)c * 256 + t];
    { // P 2-way split, cvt_pk paired along i: one op converts 2 elems AND packs the word
      const float4* raw4 = (const float4*)rawP;
#pragma unroll
      for (int r = 0; r < 2; ++r) {
        const int f0 = ((t >> 1) << 2) + (t & 1) + r * 1024;   // i-adjacent pair f0, f0+2
        float4 va = raw4[f0], vb = raw4[f0 + 2];
        const int nn = (f0 >> 6) & 31, i0 = (f0 & 63) >> 1, kk4 = (f0 & 1) << 2;
        float ea[4] = {va.x, va.y, va.z, va.w};
        float eb[4] = {vb.x, vb.y, vb.z, vb.w};
#pragma unroll
        for (int jj = 0; jj < 4; ++jj) {
          const int row = (kk4 + jj) * 32 + nn;
          unsigned hi, lo;
          asm("v_cvt_pk_bf16_f32 %0, %1, %2" : "=v"(hi) : "v"(ea[jj]), "v"(eb[jj]));
          float r0 = ea[jj] - __uint_as_float(hi << 16);          // exact residuals
          float r1 = eb[jj] - __uint_as_float(hi & 0xFFFF0000u);
          asm("v_cvt_pk_bf16_f32 %0, %1, %2" : "=v"(lo) : "v"(r0), "v"(r1));
          *(unsigned*)&sPb0[row][i0] = hi;     // i0 even: aligned b32, 2-way banks (free)
          *(unsigned*)&sPb1[row][i0] = lo;
        }
      }
    }
    { // colorT: [y][n] bf16
      int n = t >> 4, y4 = (t & 15) * 4;
      sCol[y4+0][n] = f2bf(cpf.x);
      sCol[y4+1][n] = f2bf(cpf.y);
      sCol[y4+2][n] = f2bf(cpf.z);
      sCol[y4+3][n] = f2bf(cpf.w);
    }
    if (t < 256) { sPosP[t&7][t>>3] = mpf.x; sInv[t&7][t>>3] = mpf.y; }
    __syncthreads();                           // sPb ready; rawP fully consumed
    if (c + 1 < cend) ISSUE_P(c + 1);          // DMA next chunk under compute (0 VGPR)

    // ---- compute: screen (S^T) -> exp -> PV(K=32), all register-local ----
#pragma unroll
    for (int kk = 0; kk < 4; ++kk) {
      const int k = k0 + kk;
      FragU gb;
      { // s = 0 half: n = lc (rows k*32 + 0..15)
        const int prow = k*32 + lc;
        short8 p0 = *(const short8*)&sPb0[prow][lg*8];
        short8 p1 = *(const short8*)&sPb1[prow][lg*8];
        f32x4 S = (f32x4){0.f,0.f,0.f,0.f};
        S = __builtin_amdgcn_mfma_f32_16x16x32_bf16(p1, xf1, S, 0, 0, 0);
        S = __builtin_amdgcn_mfma_f32_16x16x32_bf16(p1, xf0, S, 0, 0, 0);
        S = __builtin_amdgcn_mfma_f32_16x16x32_bf16(p0, xf1, S, 0, 0, 0);
        S = __builtin_amdgcn_mfma_f32_16x16x32_bf16(p0, xf0, S, 0, 0, 0);
        float4 pp = *(const float4*)&sPosP[k][lg*4];
        float4 iv = *(const float4*)&sInv[k][lg*4];
        float d0 = S[0]-pp.x, d1 = S[1]-pp.y, d2 = S[2]-pp.z, d3 = S[3]-pp.w;
        float g0 = __builtin_amdgcn_exp2f(d0*d0*iv.x);
        float g1 = __builtin_amdgcn_exp2f(d1*d1*iv.y);
        float g2 = __builtin_amdgcn_exp2f(d2*d2*iv.z);
        float g3 = __builtin_amdgcn_exp2f(d3*d3*iv.w);
        asm("v_cvt_pk_bf16_f32 %0, %1, %2" : "=v"(gb.u[0]) : "v"(g0), "v"(g1));
        asm("v_cvt_pk_bf16_f32 %0, %1, %2" : "=v"(gb.u[1]) : "v"(g2), "v"(g3));
      }
      { // s = 1 half: n = 16 + lc (rows k*32 + 16..31)
        const int prow = k*32 + 16 + lc;
        short8 p0 = *(const short8*)&sPb0[prow][lg*8];
        short8 p1 = *(const short8*)&sPb1[prow][lg*8];
        f32x4 S = (f32x4){0.f,0.f,0.f,0.f};
        S = __builtin_amdgcn_mfma_f32_16x16x32_bf16(p1, xf1, S, 0, 0, 0);
        S = __builtin_amdgcn_mfma_f32_16x16x32_bf16(p1, xf0, S, 0, 0, 0);
        S = __builtin_amdgcn_mfma_f32_16x16x32_bf16(p0, xf1, S, 0, 0, 0);
        S = __builtin_amdgcn_mfma_f32_16x16x32_bf16(p0, xf0, S, 0, 0, 0);
        float4 pp = *(const float4*)&sPosP[k][16 + lg*4];
        float4 iv = *(const float4*)&sInv[k][16 + lg*4];
        float d0 = S[0]-pp.x, d1 = S[1]-pp.y, d2 = S[2]-pp.z, d3 = S[3]-pp.w;
        float g0 = __builtin_amdgcn_exp2f(d0*d0*iv.x);
        float g1 = __builtin_amdgcn_exp2f(d1*d1*iv.y);
        float g2 = __builtin_amdgcn_exp2f(d2*d2*iv.z);
        float g3 = __builtin_amdgcn_exp2f(d3*d3*iv.w);
        asm("v_cvt_pk_bf16_f32 %0, %1, %2" : "=v"(gb.u[2]) : "v"(g0), "v"(g1));
        asm("v_cvt_pk_bf16_f32 %0, %1, %2" : "=v"(gb.u[3]) : "v"(g2), "v"(g3));
      }
      // PV, full K=32: B slots j=0..3 <-> n=lg*4+j (s=0), j=4..7 <-> n=16+lg*4+(j-4).
      // A (color^T) uses the same K-permutation; consistent permutation cancels in MFMA.
#pragma unroll
      for (int ys = 0; ys < 4; ++ys) {
        FragU af;
        *(uint2*)&af.u[0] = *(const uint2*)&sCol[ys*16 + lc][lg*4];
        *(uint2*)&af.u[2] = *(const uint2*)&sCol[ys*16 + lc][16 + lg*4];
        acc[kk][ys] = __builtin_amdgcn_mfma_f32_16x16x32_bf16(af.s8, gb.s8,
                                                              acc[kk][ys], 0, 0, 0);
      }
    }
  }
  __syncthreads();                             // compute done before epilogue overlay

  // ---- epilogue: transpose acc via LDS, coalesced partial write ----
  float* epi = (float*)sPool + w * (64*17);    // per-wave [64y][17] f32
#pragma unroll
  for (int kk = 0; kk < 4; ++kk) {
    const int k = k0 + kk;
#pragma unroll
    for (int ys = 0; ys < 4; ++ys) {
#pragma unroll
      for (int r = 0; r < 4; ++r)
        epi[(ys*16 + lg*4 + r)*17 + lc] = acc[kk][ys][r];
    }
    __syncthreads();
#pragma unroll
    for (int it = 0; it < 4; ++it) {
      int bi = it*4 + lg, y0 = lc*4;
      float4 v = { epi[(y0+0)*17 + bi], epi[(y0+1)*17 + bi],
                   epi[(y0+2)*17 + bi], epi[(y0+3)*17 + bi] };
      *(float4*)&pb[(size_t)(bt*16 + bi)*512 + k*64 + y0] = v;
    }
    __syncthreads();
  }
}

// ---------------- reduce: out = sum of NR partials ----------------
__global__ __launch_bounds__(512)
void gaf_reduce(const float* __restrict__ partial, float* __restrict__ out, int NR) {
  const int b = blockIdx.x;                    // global b
  const int s = b >> 6, bl = b & 63;
  const int t = threadIdx.x;                   // (k,y) flat 0..511
  float a0 = 0.f, a1 = 0.f, a2 = 0.f, a3 = 0.f;
  int nr = 0;
  for (; nr + 4 <= NR; nr += 4) {
    a0 += partial[(size_t)((nr+0)*4 + s)*PART_FLOATS + bl*512 + t];
    a1 += partial[(size_t)((nr+1)*4 + s)*PART_FLOATS + bl*512 + t];
    a2 += partial[(size_t)((nr+2)*4 + s)*PART_FLOATS + bl*512 + t];
    a3 += partial[(size_t)((nr+3)*4 + s)*PART_FLOATS + bl*512 + t];
  }
  for (; nr < NR; ++nr)
    a0 += partial[(size_t)(nr*4 + s)*PART_FLOATS + bl*512 + t];
  out[(size_t)b*512 + t] = (a0 + a1) + (a2 + a3);
}

extern "C" void kernel_launch(void* const* d_in, const int* in_sizes, int n_in,
                              void* d_out, int out_size, void* d_ws, size_t ws_size,
                              hipStream_t stream) {
  const float* x    = (const float*)d_in[0];
  const float* pos  = (const float*)d_in[1];
  const float* proj = (const float*)d_in[2];
  const float* colr = (const float*)d_in[3];
  const float* sig  = (const float*)d_in[4];
  float* out = (float*)d_out;

  float2* meta    = (float2*)d_ws;
  float*  partial = (float*)((char*)d_ws + META_BYTES);

  size_t avail = (ws_size > META_BYTES) ? ws_size - META_BYTES : 0;
  int NR = (int)(avail / (4ull * PART_FLOATS * 4ull));  // 512 KB per NR step
  if (NR > 128) NR = 128;
  if (NR < 1)  NR = 1;
  if (NR >= 8) NR &= ~7;                       // multiple of 8 for the XCD swizzle
  int NCH = (NCHUNKS + NR - 1) / NR;

  gaf_pre<<<(NTOT*KK)/256, 256, 0, stream>>>(pos, proj, sig, meta);
  gaf_main<<<4*NR, 512, 0, stream>>>(x, proj, colr, meta, partial, NCH, NR);
  gaf_reduce<<<256, 512, 0, stream>>>(partial, out, NR);
}

// Round 14
// 105.400 us; speedup vs baseline: 3.4201x; 1.0039x over previous
//
#include <hip/hip_runtime.h>

// GaussianActionField: out[b][k][y] = sum_n exp(-(x[b]·P[n,:,k] - posP[n][k])^2 / (2 s^2)) * color[n][y]
// B=256 N=65536 XD=32 YD=64 K=8.
// Dense attention-style (R13 math, verified; R14 = conflict-free LDS layouts only):
//   screen GEMM (swapped: S^T = P·x, exact 2x2 bf16 split, 4 MFMA) -> in-register exp2
//   -> cvt_pk bf16 -> PV GEMM (out^T += color^T · G) at full K=32.
//   sPb layout [ks=k*2+s][lane][8]: wave fragment reads are 1 KB contiguous (0 conflicts).
//   rawP padded 65 float4/n + bijective staging remap: DMA-read pairs and sPb writes
//   both bank-uniform. sCol staged row-wise via b64 writes (~2-way).
//   P DMA'd via global_load_lds (0 VGPR) during compute; XCD sibling swizzle for L2.
// gaf_pre: meta[n][k] = (posP, -log2e/(2 s^2)) table (4 MB in ws).
// gaf_reduce: out = sum over NR partials.

typedef __attribute__((ext_vector_type(8))) short short8;
typedef __attribute__((ext_vector_type(4))) float f32x4;

#define NTOT   65536
#define XD     32
#define YD     64
#define KK     8
#define META_BYTES (NTOT*KK*8)     // float2 per (n,k) = 4 MB
#define PART_FLOATS 32768          // per block: 64b x 8k x 64y
#define NCHUNKS 2048               // 32-n chunks
#define CSTR   40                  // sCol row stride (u16)

__device__ __forceinline__ void gload16(const void* g, void* l) {
  __builtin_amdgcn_global_load_lds(
      (const __attribute__((address_space(1))) unsigned*)g,
      (__attribute__((address_space(3))) unsigned*)l, 16, 0, 0);
}

union FragU { unsigned u[4]; short8 s8; };

// ---------------- pre: posP + exponent scale table ----------------
__global__ __launch_bounds__(256)
void gaf_pre(const float* __restrict__ pos, const float* __restrict__ proj,
             const float* __restrict__ sig, float2* __restrict__ meta) {
  int gid = blockIdx.x * 256 + threadIdx.x;    // (n,k) flat
  int n = gid >> 3, k = gid & 7;
  const float*  pk = proj + (size_t)n * XD * KK + k;
  const float4* pg = (const float4*)(pos + (size_t)n * XD);
  float d = 0.f;
#pragma unroll
  for (int j = 0; j < 8; ++j) {
    float4 v = pg[j];
    d = fmaf(v.x, pk[(4*j+0)*KK], d);
    d = fmaf(v.y, pk[(4*j+1)*KK], d);
    d = fmaf(v.z, pk[(4*j+2)*KK], d);
    d = fmaf(v.w, pk[(4*j+3)*KK], d);
  }
  float s = sig[gid];
  meta[gid] = make_float2(d, -0.72134752044448169f / (s * s));
}

// ---------------- main: dense screen->exp->PV, register-fused ----------------
__global__ __launch_bounds__(512, 4)
void gaf_main(const float* __restrict__ x, const float* __restrict__ proj,
              const float* __restrict__ colr, const float2* __restrict__ meta,
              float* __restrict__ partial, int NCH, int NR) {
  // pool: sPb0[16][512] u16 (16KB) | sPb1[16][512] u16 (16KB) | sCol[64][40] u16 (5120B)
  __shared__ __align__(16) unsigned short sPool[16*512*2 + 64*CSTR];   // 37888 B
  __shared__ float sPosP[8][36];
  __shared__ float sInv[8][36];
  __shared__ __align__(16) float rawP[32*260];         // padded: 65 float4 per n (33280 B)
  unsigned short* sPb0 = sPool;                        // [ks][l*8+j]
  unsigned short* sPb1 = sPool + 16*512;
  unsigned short (*sCol)[CSTR] = (unsigned short(*)[CSTR])(sPool + 2*16*512);

  const int t = threadIdx.x, l = t & 63, w = t >> 6;

  // ---- XCD sibling swizzle (bijective when NR%8==0) ----
  int nr, sblk;
  {
    const int gid = blockIdx.x;
    if ((NR & 7) == 0) {
      const int xcd = gid & 7, j = gid >> 3;   // consecutive gid round-robin XCDs
      nr   = xcd * (NR >> 3) + (j >> 2);       // 4 siblings share xcd
      sblk = j & 3;
    } else { nr = gid >> 2; sblk = gid & 3; }
  }

  const int bt = w & 3, k0 = (w >> 2) * 4;     // wave: b-tile bt, k's k0..k0+3
  const int lc = l & 15, lg = l >> 4;          // lane col / group
  const int cbeg = nr * NCH;
  int cend = cbeg + NCH; if (cend > NCHUNKS) cend = NCHUNKS;

  float* pb = partial + (size_t)(nr * 4 + sblk) * PART_FLOATS;   // logical slot
  if (cbeg >= cend) {                          // idle block: zero partial
    float4 z = {0.f,0.f,0.f,0.f};
#pragma unroll
    for (int r = 0; r < PART_FLOATS/4/512; ++r) ((float4*)pb)[t + r*512] = z;
    return;
  }

  // x B-fragments (2-way bf16 split), wave's b-tile: lane holds x[b=lc][i=lg*8+j]
  short8 xf0, xf1;
  {
    const int brow = sblk*64 + bt*16 + lc;
    const float4* xr = (const float4*)(x + (size_t)brow*XD + lg*8);
    float4 u0 = xr[0], u1 = xr[1];
    float xv[8] = {u0.x,u0.y,u0.z,u0.w,u1.x,u1.y,u1.z,u1.w};
#pragma unroll
    for (int j = 0; j < 8; ++j) {
      unsigned u = __float_as_uint(xv[j]);
      unsigned short h0 = (unsigned short)(u >> 16);        // trunc (exact residual)
      float r1 = xv[j] - __uint_as_float(u & 0xFFFF0000u);
      unsigned ur = __float_as_uint(r1);
      ur += 0x7FFFu + ((ur >> 16) & 1u);                    // RNE
      xf0[j] = (short)h0;
      xf1[j] = (short)(unsigned short)(ur >> 16);
    }
  }

  f32x4 acc[4][4];                             // [k-kk][y-subtile]
#pragma unroll
  for (int a = 0; a < 4; ++a)
#pragma unroll
    for (int b = 0; b < 4; ++b) acc[a][b] = (f32x4){0.f,0.f,0.f,0.f};

  // staging mapping constants (bijective thread -> (n, ip, kp))
  const int kp  = l & 1;
  const int ipL = (l >> 1) & 3;
  const int nS  = ((l >> 3) & 7) | ((w & 3) << 3);          // n = 0..31
  const int sS  = nS >> 4;
  const int ldst= (nS & 15);

  // P chunk DMA: one n per wave-instr, padded dest base n*1040 B
  auto ISSUE_P = [&](int c) {
    const float4* Pg = (const float4*)(proj + (size_t)c * 32 * XD * KK);
#pragma unroll
    for (int r2 = 0; r2 < 4; ++r2) {
      const int nd = w + r2*8;
      gload16(Pg + nd*64 + l, &rawP[nd*260]);
    }
  };

  ISSUE_P(cbeg);
  for (int c = cbeg; c < cend; ++c) {
    __syncthreads();                           // rawP[c] arrived; sPb free (compute done)
    // ---- stage chunk c ----
    // issue color (row-gather) + meta loads first; latency hides under the P-split
    const int yq = w*8 + (l>>3);               // y = 0..63
    const int nq = (l&7)*4;
    const float* cb = colr + (size_t)(c*32 + nq)*YD + yq;
    float c0 = cb[0], c1 = cb[YD], c2 = cb[2*YD], c3 = cb[3*YD];
    float2 mpf;
    if (t < 256) mpf = meta[(size_t)c * 256 + t];
    { // P 2-way split from padded rawP -> sPb[ks][l_dst][...] (all bank-uniform)
      const float4* raw4 = (const float4*)rawP;
#pragma unroll
      for (int r = 0; r < 2; ++r) {
        const int ip = ipL | (((w >> 2) & 1) << 2) | (r << 3);   // 0..15; i0 = 2*ip
        const int f0 = nS * 65 + ip * 4 + kp;
        float4 va = raw4[f0], vb = raw4[f0 + 2];
        const int l_dst = ldst | ((ip >> 2) << 4);
        const int wd = ip & 3;
        float ea[4] = {va.x, va.y, va.z, va.w};
        float eb[4] = {vb.x, vb.y, vb.z, vb.w};
#pragma unroll
        for (int jj = 0; jj < 4; ++jj) {
          const int ks = (kp*4 + jj)*2 + sS;
          unsigned hi, lo;
          asm("v_cvt_pk_bf16_f32 %0, %1, %2" : "=v"(hi) : "v"(ea[jj]), "v"(eb[jj]));
          float r0 = ea[jj] - __uint_as_float(hi << 16);          // exact residuals
          float r1 = eb[jj] - __uint_as_float(hi & 0xFFFF0000u);
          asm("v_cvt_pk_bf16_f32 %0, %1, %2" : "=v"(lo) : "v"(r0), "v"(r1));
          ((unsigned*)sPb0)[ks*256 + l_dst*4 + wd] = hi;
          ((unsigned*)sPb1)[ks*256 + l_dst*4 + wd] = lo;
        }
      }
    }
    { // colorT row-write: 2 cvt_pk -> one aligned b64 (~2-way banks)
      unsigned w0, w1;
      asm("v_cvt_pk_bf16_f32 %0, %1, %2" : "=v"(w0) : "v"(c0), "v"(c1));
      asm("v_cvt_pk_bf16_f32 %0, %1, %2" : "=v"(w1) : "v"(c2), "v"(c3));
      *(uint2*)&sCol[yq][nq] = make_uint2(w0, w1);
    }
    if (t < 256) { sPosP[t&7][t>>3] = mpf.x; sInv[t&7][t>>3] = mpf.y; }
    __syncthreads();                           // sPb ready; rawP fully consumed
    if (c + 1 < cend) ISSUE_P(c + 1);          // DMA next chunk under compute (0 VGPR)

    // ---- compute: screen (S^T) -> exp -> PV(K=32), all register-local ----
#pragma unroll
    for (int kk = 0; kk < 4; ++kk) {
      const int k = k0 + kk;
      FragU gb;
      { // s = 0 half: n = lc
        short8 p0 = *(const short8*)&sPb0[(k*2+0)*512 + l*8];    // contiguous 1KB/wave
        short8 p1 = *(const short8*)&sPb1[(k*2+0)*512 + l*8];
        f32x4 S = (f32x4){0.f,0.f,0.f,0.f};
        S = __builtin_amdgcn_mfma_f32_16x16x32_bf16(p1, xf1, S, 0, 0, 0);
        S = __builtin_amdgcn_mfma_f32_16x16x32_bf16(p1, xf0, S, 0, 0, 0);
        S = __builtin_amdgcn_mfma_f32_16x16x32_bf16(p0, xf1, S, 0, 0, 0);
        S = __builtin_amdgcn_mfma_f32_16x16x32_bf16(p0, xf0, S, 0, 0, 0);
        float4 pp = *(const float4*)&sPosP[k][lg*4];
        float4 iv = *(const float4*)&sInv[k][lg*4];
        float d0 = S[0]-pp.x, d1 = S[1]-pp.y, d2 = S[2]-pp.z, d3 = S[3]-pp.w;
        float g0 = __builtin_amdgcn_exp2f(d0*d0*iv.x);
        float g1 = __builtin_amdgcn_exp2f(d1*d1*iv.y);
        float g2 = __builtin_amdgcn_exp2f(d2*d2*iv.z);
        float g3 = __builtin_amdgcn_exp2f(d3*d3*iv.w);
        asm("v_cvt_pk_bf16_f32 %0, %1, %2" : "=v"(gb.u[0]) : "v"(g0), "v"(g1));
        asm("v_cvt_pk_bf16_f32 %0, %1, %2" : "=v"(gb.u[1]) : "v"(g2), "v"(g3));
      }
      { // s = 1 half: n = 16 + lc
        short8 p0 = *(const short8*)&sPb0[(k*2+1)*512 + l*8];
        short8 p1 = *(const short8*)&sPb1[(k*2+1)*512 + l*8];
        f32x4 S = (f32x4){0.f,0.f,0.f,0.f};
        S = __builtin_amdgcn_mfma_f32_16x16x32_bf16(p1, xf1, S, 0, 0, 0);
        S = __builtin_amdgcn_mfma_f32_16x16x32_bf16(p1, xf0, S, 0, 0, 0);
        S = __builtin_amdgcn_mfma_f32_16x16x32_bf16(p0, xf1, S, 0, 0, 0);
        S = __builtin_amdgcn_mfma_f32_16x16x32_bf16(p0, xf0, S, 0, 0, 0);
        float4 pp = *(const float4*)&sPosP[k][16 + lg*4];
        float4 iv = *(const float4*)&sInv[k][16 + lg*4];
        float d0 = S[0]-pp.x, d1 = S[1]-pp.y, d2 = S[2]-pp.z, d3 = S[3]-pp.w;
        float g0 = __builtin_amdgcn_exp2f(d0*d0*iv.x);
        float g1 = __builtin_amdgcn_exp2f(d1*d1*iv.y);
        float g2 = __builtin_amdgcn_exp2f(d2*d2*iv.z);
        float g3 = __builtin_amdgcn_exp2f(d3*d3*iv.w);
        asm("v_cvt_pk_bf16_f32 %0, %1, %2" : "=v"(gb.u[2]) : "v"(g0), "v"(g1));
        asm("v_cvt_pk_bf16_f32 %0, %1, %2" : "=v"(gb.u[3]) : "v"(g2), "v"(g3));
      }
      // PV, full K=32: B slots j=0..3 <-> n=lg*4+j (s=0), j=4..7 <-> n=16+lg*4+(j-4).
      // A (color^T) uses the same K-permutation; consistent permutation cancels in MFMA.
#pragma unroll
      for (int ys = 0; ys < 4; ++ys) {
        FragU af;
        *(uint2*)&af.u[0] = *(const uint2*)&sCol[ys*16 + lc][lg*4];
        *(uint2*)&af.u[2] = *(const uint2*)&sCol[ys*16 + lc][16 + lg*4];
        acc[kk][ys] = __builtin_amdgcn_mfma_f32_16x16x32_bf16(af.s8, gb.s8,
                                                              acc[kk][ys], 0, 0, 0);
      }
    }
  }
  __syncthreads();                             // compute done before epilogue overlay

  // ---- epilogue: transpose acc via LDS, coalesced partial write ----
  float* epi = (float*)sPool + w * (64*17);    // per-wave [64y][17] f32 (34816 B < pool)
#pragma unroll
  for (int kk = 0; kk < 4; ++kk) {
    const int k = k0 + kk;
#pragma unroll
    for (int ys = 0; ys < 4; ++ys) {
#pragma unroll
      for (int r = 0; r < 4; ++r)
        epi[(ys*16 + lg*4 + r)*17 + lc] = acc[kk][ys][r];
    }
    __syncthreads();
#pragma unroll
    for (int it = 0; it < 4; ++it) {
      int bi = it*4 + lg, y0 = lc*4;
      float4 v = { epi[(y0+0)*17 + bi], epi[(y0+1)*17 + bi],
                   epi[(y0+2)*17 + bi], epi[(y0+3)*17 + bi] };
      *(float4*)&pb[(size_t)(bt*16 + bi)*512 + k*64 + y0] = v;
    }
    __syncthreads();
  }
}

// ---------------- reduce: out = sum of NR partials ----------------
__global__ __launch_bounds__(512)
void gaf_reduce(const float* __restrict__ partial, float* __restrict__ out, int NR) {
  const int b = blockIdx.x;                    // global b
  const int s = b >> 6, bl = b & 63;
  const int t = threadIdx.x;                   // (k,y) flat 0..511
  float a0 = 0.f, a1 = 0.f, a2 = 0.f, a3 = 0.f;
  int nr = 0;
  for (; nr + 4 <= NR; nr += 4) {
    a0 += partial[(size_t)((nr+0)*4 + s)*PART_FLOATS + bl*512 + t];
    a1 += partial[(size_t)((nr+1)*4 + s)*PART_FLOATS + bl*512 + t];
    a2 += partial[(size_t)((nr+2)*4 + s)*PART_FLOATS + bl*512 + t];
    a3 += partial[(size_t)((nr+3)*4 + s)*PART_FLOATS + bl*512 + t];
  }
  for (; nr < NR; ++nr)
    a0 += partial[(size_t)(nr*4 + s)*PART_FLOATS + bl*512 + t];
  out[(size_t)b*512 + t] = (a0 + a1) + (a2 + a3);
}

extern "C" void kernel_launch(void* const* d_in, const int* in_sizes, int n_in,
                              void* d_out, int out_size, void* d_ws, size_t ws_size,
                              hipStream_t stream) {
  const float* x    = (const float*)d_in[0];
  const float* pos  = (const float*)d_in[1];
  const float* proj = (const float*)d_in[2];
  const float* colr = (const float*)d_in[3];
  const float* sig  = (const float*)d_in[4];
  float* out = (float*)d_out;

  float2* meta    = (float2*)d_ws;
  float*  partial = (float*)((char*)d_ws + META_BYTES);

  size_t avail = (ws_size > META_BYTES) ? ws_size - META_BYTES : 0;
  int NR = (int)(avail / (4ull * PART_FLOATS * 4ull));  // 512 KB per NR step
  if (NR > 128) NR = 128;
  if (NR < 1)  NR = 1;
  if (NR >= 8) NR &= ~7;                       // multiple of 8 for the XCD swizzle
  int NCH = (NCHUNKS + NR - 1) / NR;

  gaf_pre<<<(NTOT*KK)/256, 256, 0, stream>>>(pos, proj, sig, meta);
  gaf_main<<<4*NR, 512, 0, stream>>>(x, proj, colr, meta, partial, NCH, NR);
  gaf_reduce<<<256, 512, 0, stream>>>(partial, out, NR);
}